// Round 12
// baseline (2446.319 us; speedup 1.0000x reference)
//
#include <hip/hip_runtime.h>
#include <math.h>

// GRU seq2seq on MI355X. Round 10 source, resubmit (infra timeout, no signal).
// Occupancy attack on the latency-bound GEMMs: BK 64->32 halves LDS (enc 28KB, dec
// 24KB) -> 4 blocks/CU resident (was 2), so the 1024-block encoder pair
// {E1_t || E0_{t+1}} is FULLY concurrent, and the decoder moves to 64-row m-tiles
// (grid 1024, 4/CU). Core: gemm_core32<MI,NJ,KTOT,SPLIT>, 2-phase dbuf, one barrier
// per K-tile, 4-chunk XOR swizzle both sides. E1 split n-accumulator (NJ=3, K=1024).
// D carries the fc fragment (NJ=4) -> pred via 2 shfls, plain stores. fp32 master h.

#define B_SZ  4096
#define H     512
#define TOBS  30
#define TPRED 60

typedef float f32x4 __attribute__((ext_vector_type(4)));
typedef short s16x8 __attribute__((ext_vector_type(8)));
typedef __bf16 bf16x8 __attribute__((ext_vector_type(8)));

__device__ __forceinline__ float b2f(unsigned short u) {
    unsigned v = (unsigned)u << 16; return __builtin_bit_cast(float, v);
}
__device__ __forceinline__ unsigned short f2b(float f) {  // RNE
    unsigned u = __builtin_bit_cast(unsigned, f);
    return (unsigned short)((u + 0x7FFF + ((u >> 16) & 1)) >> 16);
}

typedef __attribute__((address_space(1))) void gvoid;
typedef __attribute__((address_space(3))) void lvoid;
__device__ __forceinline__ void gl16(const void* g, void* l) {
    __builtin_amdgcn_global_load_lds((gvoid*)g, (lvoid*)l, 16, 0, 0);
}

__device__ __forceinline__ f32x4 mfma_bf16(s16x8 a, s16x8 b, f32x4 c) {
    return __builtin_amdgcn_mfma_f32_16x16x32_bf16(
        __builtin_bit_cast(bf16x8, a), __builtin_bit_cast(bf16x8, b), c, 0, 0, 0);
}

__device__ __forceinline__ float sigmoidf_(float v) { return 1.f / (1.f + expf(-v)); }

// 2-phase double-buffered GEMM core, BK=32. Tile (32*MI)m x (32*NJ)n, 4 waves (2x2).
// A row-stride 512; SPLIT: K-tiles with k0>=512 read A1 (E1's [h0|h1] concat) and the
// last fragment accumulates into acc[][NJ] for ti>=NT/2. One __syncthreads per K-tile.
template<int MI, int NJ, int KTOT, int SPLIT>
__device__ __forceinline__ void gemm_core32(
    const unsigned short* __restrict__ A0, const unsigned short* __restrict__ A1,
    const unsigned short* __restrict__ W,
    int m0, int n0,
    unsigned short* __restrict__ sA, unsigned short* __restrict__ sB,
    f32x4 (&acc)[MI][NJ + SPLIT])
{
    const int tid  = threadIdx.x;
    const int lane = tid & 63;
    const int w    = tid >> 6;
    const int wr = w >> 1, wc = w & 1;
    const int lr = lane & 15;
    const int q  = lane >> 4;            // k-chunk 0..3 (8 bf16 each)
    const int wbase = tid & ~63;
    const int NT  = KTOT / 32;
    const int ASZ = MI * 1024, BSZ = NJ * 1024;   // elements per buffer
    const int RA  = (MI * 128) / 256;             // A staging rounds (MI in {2,4})
    const int RB  = (NJ * 128 + 255) / 256;       // B staging rounds (guarded)

    auto stage = [&](int buf, int k0) {
        unsigned short* dA = sA + buf * ASZ;
        unsigned short* dB = sB + buf * BSZ;
        const unsigned short* Ab = (SPLIT && k0 >= 512) ? A1 : A0;
        const int ak0 = (SPLIT && k0 >= 512) ? k0 - 512 : k0;
#pragma unroll
        for (int s = 0; s < RA; ++s) {
            int i = s * 256 + tid;
            int row = i >> 2, p = i & 3;
            int c = p ^ (row & 3);
            gl16(Ab + (size_t)(m0 + row) * 512 + ak0 + c * 8, dA + (s * 256 + wbase) * 8);
        }
#pragma unroll
        for (int s = 0; s < RB; ++s) {
            if (s * 256 + wbase < NJ * 128) {     // wave-uniform guard
                int i = s * 256 + tid;
                int row = i >> 2, p = i & 3;
                int c = p ^ (row & 3);
                gl16(W + (size_t)(n0 + row) * KTOT + k0 + c * 8, dB + (s * 256 + wbase) * 8);
            }
        }
    };

    stage(0, 0);
    __syncthreads();
#pragma unroll
    for (int ti = 0; ti < NT; ++ti) {
        const int cur = ti & 1;
        if (ti + 1 < NT) stage(cur ^ 1, (ti + 1) * 32);
        const unsigned short* cA = sA + cur * ASZ;
        const unsigned short* cB = sB + cur * BSZ;
        s16x8 af[MI], bf[NJ];
#pragma unroll
        for (int fi = 0; fi < MI; ++fi) {
            int r = wr * (MI * 16) + fi * 16 + lr;
            af[fi] = *(const s16x8*)&cA[r * 32 + ((q ^ (r & 3)) * 8)];
        }
#pragma unroll
        for (int fj = 0; fj < NJ; ++fj) {
            int r = wc * (NJ * 16) + fj * 16 + lr;
            bf[fj] = *(const s16x8*)&cB[r * 32 + ((q ^ (r & 3)) * 8)];
        }
#pragma unroll
        for (int fi = 0; fi < MI; ++fi)
#pragma unroll
            for (int fj = 0; fj < NJ; ++fj) {
                const int dst = (SPLIT && fj == NJ - 1 && ti >= NT / 2) ? NJ : fj;
                acc[fi][dst] = mfma_bf16(af[fi], bf[fj], acc[fi][dst]);
            }
        __syncthreads();
    }
}

// Paired encoder kernel. roles: 1=E1 only, 2=E0 only, 3=both (grid 1024, bid<512 -> E1).
// E1: [gi1|gh1] GEMM MI=4,NJ=3,K=1024 (A=[h0_{t+1}|h1_t]), split n-acc, + cell1.
// E0: gh0 GEMM MI=4,NJ=3,K=512, + cell0 (x-side K=4 inline fp32).
__global__ __launch_bounds__(256)
void gemm_enc(const unsigned short* __restrict__ e1_h0, const unsigned short* __restrict__ e1_h1in,
              unsigned short* __restrict__ e1_h1out, const unsigned short* __restrict__ W1,
              const float* __restrict__ bih1, const float* __restrict__ bhh1,
              float* __restrict__ hf1,
              const unsigned short* __restrict__ e0_h0in, unsigned short* __restrict__ e0_h0out,
              const unsigned short* __restrict__ W0,
              const float* __restrict__ x, int t,
              const float* __restrict__ Wih0, const float* __restrict__ bih0,
              const float* __restrict__ bhh0, float* __restrict__ hf0,
              int roles)
{
    __shared__ unsigned short sA[2 * 128 * 32], sB[2 * 96 * 32];

    int bid = (int)blockIdx.x;
    bool isE1;
    if (roles == 3) { isE1 = bid < 512; bid &= 511; }
    else            { isE1 = (roles == 1); }

    int swz = (bid & 7) * 64 + (bid >> 3);
    const int tile_n = swz & 15;
    const int n0 = tile_n * 96;
    const int m0 = (swz >> 4) * 128;

    const int lane = threadIdx.x & 63;
    const int w    = threadIdx.x >> 6;
    const int wrw = w >> 1, wcw = w & 1;
    const int lr = lane & 15, q = lane >> 4;
    const int u = tile_n * 32 + wcw * 16 + lr;

    if (isE1) {
        f32x4 acc[4][4];
#pragma unroll
        for (int i = 0; i < 4; ++i)
#pragma unroll
            for (int j = 0; j < 4; ++j) acc[i][j] = (f32x4){0.f, 0.f, 0.f, 0.f};

        gemm_core32<4, 3, 1024, 1>(e1_h0, e1_h1in, W1, m0, n0, sA, sB, acc);

        float br_ = bih1[u] + bhh1[u];
        float bz_ = bih1[512 + u] + bhh1[512 + u];
        float bni = bih1[1024 + u], bnh = bhh1[1024 + u];
#pragma unroll
        for (int fi = 0; fi < 4; ++fi) {
#pragma unroll
            for (int j = 0; j < 4; ++j) {
                int row = m0 + wrw * 64 + fi * 16 + q * 4 + j;
                float rr = sigmoidf_(acc[fi][0][j] + br_);
                float zz = sigmoidf_(acc[fi][1][j] + bz_);
                float nn = tanhf(acc[fi][2][j] + bni + rr * (acc[fi][3][j] + bnh));
                size_t hidx = (size_t)row * 512 + u;
                float hn = (1.f - zz) * nn + zz * hf1[hidx];
                hf1[hidx] = hn;
                e1_h1out[hidx] = f2b(hn);
            }
        }
    } else {
        f32x4 acc[4][3];
#pragma unroll
        for (int i = 0; i < 4; ++i)
#pragma unroll
            for (int j = 0; j < 3; ++j) acc[i][j] = (f32x4){0.f, 0.f, 0.f, 0.f};

        gemm_core32<4, 3, 512, 0>(e0_h0in, e0_h0in, W0, m0, n0, sA, sB, acc);

        float4 wrv = *(const float4*)(Wih0 + (size_t)u * 4);
        float4 wzv = *(const float4*)(Wih0 + (size_t)(512 + u) * 4);
        float4 wnv = *(const float4*)(Wih0 + (size_t)(1024 + u) * 4);
        float br_ = bih0[u], bz_ = bih0[512 + u], bn_ = bih0[1024 + u];
        float cr_ = bhh0[u], cz_ = bhh0[512 + u], cn_ = bhh0[1024 + u];
#pragma unroll
        for (int fi = 0; fi < 4; ++fi) {
#pragma unroll
            for (int j = 0; j < 4; ++j) {
                int row = m0 + wrw * 64 + fi * 16 + q * 4 + j;
                float4 xv = *(const float4*)(x + (size_t)row * 120 + t * 4);
                float gir = br_ + xv.x * wrv.x + xv.y * wrv.y + xv.z * wrv.z + xv.w * wrv.w;
                float giz = bz_ + xv.x * wzv.x + xv.y * wzv.y + xv.z * wzv.z + xv.w * wzv.w;
                float gin = bn_ + xv.x * wnv.x + xv.y * wnv.y + xv.z * wnv.z + xv.w * wnv.w;
                float rr = sigmoidf_(gir + acc[fi][0][j] + cr_);
                float zz = sigmoidf_(giz + acc[fi][1][j] + cz_);
                float nn = tanhf(gin + rr * (acc[fi][2][j] + cn_));
                size_t hidx = (size_t)row * 512 + u;
                float hn = (1.f - zz) * nn + zz * hf0[hidx];
                hf0[hidx] = hn;
                e0_h0out[hidx] = f2b(hn);
            }
        }
    }
}

// D: [ghd|fc] GEMM (MI=2, NJ=4, K=512, 64-row m-tiles, grid 1024) + decoder cell.
// Fragment 3 = FC output: pred_{t-1} via 2 intra-wave shfls. Plain stores, no atomics.
__global__ __launch_bounds__(256)
void gemm_d(const unsigned short* __restrict__ A /* h1 ping */,
            const unsigned short* __restrict__ W,
            const float* __restrict__ dinbuf, int t,
            const float* __restrict__ Wih, const float* __restrict__ bih,
            const float* __restrict__ bhh, const float* __restrict__ bfc,
            float* __restrict__ hf, unsigned short* __restrict__ hbout,
            float* __restrict__ out)
{
    int bid = (int)blockIdx.x;
    int swz = (bid & 7) * 128 + (bid >> 3);   // 1024 blocks, 8 XCDs x 128
    const int tile_n = swz & 15;
    const int n0 = tile_n * 128;
    const int m0 = (swz >> 4) * 64;

    __shared__ unsigned short sA[2 * 64 * 32], sB[2 * 128 * 32];
    f32x4 acc[2][4];
#pragma unroll
    for (int i = 0; i < 2; ++i)
#pragma unroll
        for (int j = 0; j < 4; ++j) acc[i][j] = (f32x4){0.f, 0.f, 0.f, 0.f};

    gemm_core32<2, 4, 512, 0>(A, A, W, m0, n0, sA, sB, acc);

    const int lane = threadIdx.x & 63;
    const int w    = threadIdx.x >> 6;
    const int wrw = w >> 1, wcw = w & 1;
    const int lr = lane & 15, q = lane >> 4;
    const int u = tile_n * 32 + wcw * 16 + lr;

    float wr0 = Wih[(size_t)u * 2],          wr1 = Wih[(size_t)u * 2 + 1];
    float wz0 = Wih[(size_t)(512 + u) * 2],  wz1 = Wih[(size_t)(512 + u) * 2 + 1];
    float wn0 = Wih[(size_t)(1024 + u) * 2], wn1 = Wih[(size_t)(1024 + u) * 2 + 1];
    float br_ = bih[u], bz_ = bih[512 + u], bn_ = bih[1024 + u];
    float cr_ = bhh[u], cz_ = bhh[512 + u], cn_ = bhh[1024 + u];
    float bfc0 = bfc[0], bfc1 = bfc[1];
    const bool wout = (tile_n == 0) && (wcw == 0) && (lr == 0);

#pragma unroll
    for (int fi = 0; fi < 2; ++fi) {
#pragma unroll
        for (int j = 0; j < 4; ++j) {
            int row = m0 + wrw * 32 + fi * 16 + q * 4 + j;
            float p0 = __shfl(acc[fi][3][j], (lane & 48) | 0) + bfc0;
            float p1 = __shfl(acc[fi][3][j], (lane & 48) | 1) + bfc1;
            float x0, x1;
            if (t == 0) { x0 = dinbuf[row * 2]; x1 = dinbuf[row * 2 + 1]; }
            else        { x0 = p0; x1 = p1; }
            float gir = br_ + x0 * wr0 + x1 * wr1;
            float giz = bz_ + x0 * wz0 + x1 * wz1;
            float gin = bn_ + x0 * wn0 + x1 * wn1;
            float rr = sigmoidf_(gir + acc[fi][0][j] + cr_);
            float zz = sigmoidf_(giz + acc[fi][1][j] + cz_);
            float nn = tanhf(gin + rr * (acc[fi][2][j] + cn_));
            size_t hidx = (size_t)row * 512 + u;
            float hn = (1.f - zz) * nn + zz * hf[hidx];
            hf[hidx] = hn;
            hbout[hidx] = f2b(hn);
            if (t > 0 && wout) {
                out[(size_t)row * 120 + (t - 1) * 2 + 0] = p0;
                out[(size_t)row * 120 + (t - 1) * 2 + 1] = p1;
            }
        }
    }
}

// Final pred_59 = Wfc @ h_60 + bfc. One 64-lane wave per batch row.
__global__ __launch_bounds__(64)
void fc_last(const unsigned short* __restrict__ hb, const float* __restrict__ Wfc,
             const float* __restrict__ bfc, float* __restrict__ out)
{
    int row = blockIdx.x, lane = threadIdx.x;
    const unsigned short* hrow = hb + (size_t)row * 512;
    float a0 = 0.f, a1 = 0.f;
#pragma unroll
    for (int kb = 0; kb < 8; ++kb) {
        int k = kb * 64 + lane;
        float hv = b2f(hrow[k]);
        a0 += hv * Wfc[k];
        a1 += hv * Wfc[512 + k];
    }
#pragma unroll
    for (int m = 32; m; m >>= 1) { a0 += __shfl_xor(a0, m); a1 += __shfl_xor(a1, m); }
    if (lane == 0) {
        out[(size_t)row * 120 + 118] = a0 + bfc[0];
        out[(size_t)row * 120 + 119] = a1 + bfc[1];
    }
}

// W0' (1536x512): row c: ublock=c/48, g=(c%48)/16, u=ublock*16+(c%16)
__global__ void wprep_rzn(const float* __restrict__ s, unsigned short* __restrict__ d)
{
    int i = blockIdx.x * 256 + threadIdx.x;   // over 1536*512
    int c = i >> 9, k = i & 511;
    int ublock = c / 48, rem = c % 48, g = rem >> 4, uoff = rem & 15;
    int u = ublock * 16 + uoff;
    d[i] = f2b(s[((size_t)(g * 512 + u)) * 512 + k]);
}

// W1'' (1536x1024): row c as above; col k: k<512 -> Wih1 gate row, k>=512 -> Whh1.
__global__ void wprep_e1(const float* __restrict__ Wih1, const float* __restrict__ Whh1,
                         unsigned short* __restrict__ d)
{
    int i = blockIdx.x * 256 + threadIdx.x;   // over 1536*1024
    int c = i >> 10, k = i & 1023;
    int ublock = c / 48, rem = c % 48, g = rem >> 4, uoff = rem & 15;
    int u = ublock * 16 + uoff;
    float v = (k < 512) ? Wih1[(size_t)(g * 512 + u) * 512 + k]
                        : Whh1[(size_t)(g * 512 + u) * 512 + (k - 512)];
    d[i] = f2b(v);
}

// Wd' (2048x512) for D: c: ublock=c>>6, g=(c>>4)&3, uoff=c&15.
// g<3: Whhd gate rows; g==3: uoff<2 -> Wfc row uoff, else 0.
__global__ void wprep_d(const float* __restrict__ Whhd, const float* __restrict__ Wfc,
                        unsigned short* __restrict__ d)
{
    int i = blockIdx.x * 256 + threadIdx.x;   // over 2048*512
    int c = i >> 9, k = i & 511;
    int ublock = c >> 6, g = (c >> 4) & 3, uoff = c & 15;
    int u = ublock * 16 + uoff;
    float v;
    if (g < 3)           v = Whhd[((size_t)(g * 512 + u)) * 512 + k];
    else if (uoff < 2)   v = Wfc[(size_t)uoff * 512 + k];
    else                 v = 0.f;
    d[i] = f2b(v);
}

__global__ void init_all(const float* __restrict__ x,
                         float* __restrict__ hf0, float* __restrict__ hf1,
                         unsigned short* __restrict__ h0a, unsigned short* __restrict__ h1a,
                         float* __restrict__ dinbuf)
{
    int idx = blockIdx.x * 256 + threadIdx.x;  // over B*512
    hf0[idx] = 0.f; hf1[idx] = 0.f;
    h0a[idx] = 0; h1a[idx] = 0;
    if (idx < B_SZ * 2)
        dinbuf[idx] = x[(size_t)(idx >> 1) * 120 + 29 * 4 + (idx & 1)];
}

extern "C" void kernel_launch(void* const* d_in, const int* in_sizes, int n_in,
                              void* d_out, int out_size, void* d_ws, size_t ws_size,
                              hipStream_t stream)
{
    const float* x    = (const float*)d_in[0];
    const float* Wih0 = (const float*)d_in[1];
    const float* Whh0 = (const float*)d_in[2];
    const float* bih0 = (const float*)d_in[3];
    const float* bhh0 = (const float*)d_in[4];
    const float* Wih1 = (const float*)d_in[5];
    const float* Whh1 = (const float*)d_in[6];
    const float* bih1 = (const float*)d_in[7];
    const float* bhh1 = (const float*)d_in[8];
    const float* Wihd = (const float*)d_in[9];
    const float* Whhd = (const float*)d_in[10];
    const float* bihd = (const float*)d_in[11];
    const float* bhhd = (const float*)d_in[12];
    const float* Wfc  = (const float*)d_in[13];
    const float* bfc  = (const float*)d_in[14];
    float* out = (float*)d_out;

    // ws: hf0,hf1 (B*512 f32) | h0[2],h1[2] (B*512 u16 each) | dinbuf | W0' | W1'' | Wd'
    char* p = (char*)d_ws;
    float* hf0 = (float*)p;  p += (size_t)B_SZ * 512 * 4;
    float* hf1 = (float*)p;  p += (size_t)B_SZ * 512 * 4;
    unsigned short* h0b_[2], *h1b_[2];
    h0b_[0] = (unsigned short*)p; p += (size_t)B_SZ * 512 * 2;
    h0b_[1] = (unsigned short*)p; p += (size_t)B_SZ * 512 * 2;
    h1b_[0] = (unsigned short*)p; p += (size_t)B_SZ * 512 * 2;
    h1b_[1] = (unsigned short*)p; p += (size_t)B_SZ * 512 * 2;
    float* dinbuf = (float*)p; p += (size_t)B_SZ * 2 * 4;
    unsigned short* W0p  = (unsigned short*)p; p += (size_t)1536 * 512 * 2;
    unsigned short* W1pp = (unsigned short*)p; p += (size_t)1536 * 1024 * 2;
    unsigned short* Wdp  = (unsigned short*)p;

    wprep_rzn<<<(1536 * 512) / 256, 256, 0, stream>>>(Whh0, W0p);
    wprep_e1<<<(1536 * 1024) / 256, 256, 0, stream>>>(Wih1, Whh1, W1pp);
    wprep_d<<<(2048 * 512) / 256, 256, 0, stream>>>(Whhd, Wfc, Wdp);
    init_all<<<(B_SZ * 512) / 256, 256, 0, stream>>>(x, hf0, hf1, h0b_[0], h1b_[0], dinbuf);

    // Encoder. h0_t in h0b_[t&1]; h1_t in h1b_[t&1].
    // Pair P_t = {E1_{t-1}, E0_t}: E1 reads h0b_[t&1] + h1b_[(t-1)&1], writes h1b_[t&1];
    // E0 reads h0b_[t&1], writes h0b_[(t+1)&1] -> race-free.
    gemm_enc<<<512, 256, 0, stream>>>(nullptr, nullptr, nullptr, nullptr, nullptr, nullptr,
                                      nullptr,
                                      h0b_[0], h0b_[1], W0p, x, 0, Wih0, bih0, bhh0, hf0,
                                      2);
    for (int t = 1; t < TOBS; ++t) {
        int s = t - 1;
        gemm_enc<<<1024, 256, 0, stream>>>(
            h0b_[(s + 1) & 1], h1b_[s & 1], h1b_[(s + 1) & 1], W1pp, bih1, bhh1, hf1,
            h0b_[t & 1], h0b_[(t + 1) & 1], W0p, x, t, Wih0, bih0, bhh0, hf0,
            3);
    }
    {   // E1_29 solo
        int s = TOBS - 1;
        gemm_enc<<<512, 256, 0, stream>>>(
            h0b_[(s + 1) & 1], h1b_[s & 1], h1b_[(s + 1) & 1], W1pp, bih1, bhh1, hf1,
            nullptr, nullptr, nullptr, nullptr, 0, nullptr, nullptr, nullptr, nullptr,
            1);
    }
    // h1_30 in h1b_[0] (TOBS even). Decoder: h_dec_t in h1b_[t&1].
    for (int t = 0; t < TPRED; ++t) {
        gemm_d<<<1024, 256, 0, stream>>>(h1b_[t & 1], Wdp, dinbuf, t, Wihd, bihd, bhhd, bfc,
                                         hf1, h1b_[(t + 1) & 1], out);
    }
    // pred_59 = FC(h_60); h_60 in h1b_[0] (TPRED even).
    fc_last<<<B_SZ, 64, 0, stream>>>(h1b_[0], Wfc, bfc, out);
}